// Round 5
// baseline (571.351 us; speedup 1.0000x reference)
//
#include <hip/hip_runtime.h>

// Problem: B=4, S=2048, D=1024, H=16, DK=64. Causal MHA forward, fp32 in/out.
#define BB 4
#define SS 2048
#define DD 1024
#define HH 16
#define DK 64
#define MM (BB * SS)  // 8192 tokens

typedef __bf16 bf16x8 __attribute__((ext_vector_type(8)));
typedef float f32x4 __attribute__((ext_vector_type(4)));
typedef unsigned short us8 __attribute__((ext_vector_type(8)));
typedef unsigned short us4 __attribute__((ext_vector_type(4)));

#define MFMA_BF16(a, b, c) __builtin_amdgcn_mfma_f32_16x16x32_bf16((a), (b), (c), 0, 0, 0)

__device__ __forceinline__ unsigned short f2bf(float f) {
  return __builtin_bit_cast(unsigned short, (__bf16)f);  // native cvt (RNE)
}

__device__ __forceinline__ bf16x8 ld_frag(const unsigned short* p) {
  return __builtin_bit_cast(bf16x8, *(const us8*)p);
}

// async global->LDS, 16B per lane. LDS dest must be wave-uniform base + lane*16.
__device__ __forceinline__ void gl_lds16(const unsigned short* g, unsigned short* l) {
  __builtin_amdgcn_global_load_lds((const __attribute__((address_space(1))) void*)g,
                                   (__attribute__((address_space(3))) void*)l, 16, 0, 0);
}

// ---------------------------------------------------------------------------
// K0: convert the 4 weight matrices fp32 -> bf16 (1M elems each)
// ---------------------------------------------------------------------------
__global__ void cvt_weights(const float* __restrict__ w0, const float* __restrict__ w1,
                            const float* __restrict__ w2, const float* __restrict__ w3,
                            unsigned short* __restrict__ dst) {
  const float* src = (blockIdx.y == 0) ? w0 : (blockIdx.y == 1) ? w1 : (blockIdx.y == 2) ? w2 : w3;
  unsigned short* d = dst + (size_t)blockIdx.y * (DD * DD);
  int idx = (blockIdx.x * 256 + threadIdx.x) * 4;
  float4 v = *(const float4*)(src + idx);
  us4 o;
  o[0] = f2bf(v.x); o[1] = f2bf(v.y); o[2] = f2bf(v.z); o[3] = f2bf(v.w);
  *(us4*)(d + idx) = o;
}

// ---------------------------------------------------------------------------
// K1: fused QKV projection, one dispatch (z = mode). Tile 128m x 128n (2 heads
// per n-tile, 8x X reuse, same-XCD stripe sharing). BK=64 as two 32-wide
// halves (m97 layout: unpadded stride-32 LDS, lane-linear for gl_lds).
// fp32 X converted in-register during A staging; bf16 W via global_load_lds.
// Column remap: block owns n-set {dk*16 + h : h in {h0,h0+1}, dk in 0..63}.
// mode 0/1 -> (B,H,S,DK); mode 2 -> V^T (B,H,DK,S) via LDS transpose.
// ---------------------------------------------------------------------------
__global__ __launch_bounds__(256, 4) void qkv_gemm(
    const float* __restrict__ xq, const float* __restrict__ xk, const float* __restrict__ xv,
    const unsigned short* __restrict__ wb,
    const float* __restrict__ bq, const float* __restrict__ bk, const float* __restrict__ bv,
    unsigned short* __restrict__ qh, unsigned short* __restrict__ kh,
    unsigned short* __restrict__ vt) {
  const int mode = blockIdx.z;
  const float* x = (mode == 0) ? xq : (mode == 1) ? xk : xv;
  const unsigned short* w = wb + (size_t)mode * (DD * DD);
  const float* bias = (mode == 0) ? bq : (mode == 1) ? bk : bv;

  const int m0 = blockIdx.x * 128;
  const int h0 = blockIdx.y * 2;

  // sA[2][128*32] | sB[2][128*32]; V epilogue reuses as sT[128*136] (17408)
  __shared__ unsigned short smem[17408];
  unsigned short* sA = smem;
  unsigned short* sB = smem + 8192;

  const int tid = threadIdx.x;
  const int lane = tid & 63;
  const int wave = tid >> 6;
  const int wm = wave & 1, wn = wave >> 1;
  const int quad = lane >> 4, l16 = lane & 15;

  f32x4 acc[4][4];
#pragma unroll
  for (int i = 0; i < 4; i++)
#pragma unroll
    for (int j = 0; j < 4; j++) acc[i][j] = f32x4{0.f, 0.f, 0.f, 0.f};

  // A staging: thread owns row tid>>1, half tid&1 (cols half*32..+31)
  const int arow = tid >> 1, ahalf = tid & 1;
  const float* ag = x + (size_t)(m0 + arow) * DD + ahalf * 32;
  unsigned short* adst = sA + ahalf * 4096 + arow * 32;

  for (int k0 = 0; k0 < DD; k0 += 64) {
    __syncthreads();
    // stage B: 128 rows x 64 cols bf16, 4 lane-linear gl_lds calls
#pragma unroll
    for (int j = 0; j < 4; j++) {
      int cid = tid + j * 256;            // 0..1023
      int half = cid >> 9;                // 0/1 -> cols k0+half*32
      int rr = (cid & 511) >> 2;          // 0..127
      int c8 = (cid & 3) << 3;
      int n = ((rr & 63) << 4) + h0 + (rr >> 6);
      gl_lds16(w + (size_t)n * DD + k0 + half * 32 + c8,
               sB + half * 4096 + rr * 32 + c8);
    }
    // stage A: fp32 -> bf16 in regs -> 4 b128 writes (full 32-elem half-row)
    {
      const float* a = ag + k0;
      float4 v0 = *(const float4*)(a + 0);
      float4 v1 = *(const float4*)(a + 4);
      float4 v2 = *(const float4*)(a + 8);
      float4 v3 = *(const float4*)(a + 12);
      float4 v4 = *(const float4*)(a + 16);
      float4 v5 = *(const float4*)(a + 20);
      float4 v6 = *(const float4*)(a + 24);
      float4 v7 = *(const float4*)(a + 28);
      us8 o0, o1, o2, o3;
      o0[0] = f2bf(v0.x); o0[1] = f2bf(v0.y); o0[2] = f2bf(v0.z); o0[3] = f2bf(v0.w);
      o0[4] = f2bf(v1.x); o0[5] = f2bf(v1.y); o0[6] = f2bf(v1.z); o0[7] = f2bf(v1.w);
      o1[0] = f2bf(v2.x); o1[1] = f2bf(v2.y); o1[2] = f2bf(v2.z); o1[3] = f2bf(v2.w);
      o1[4] = f2bf(v3.x); o1[5] = f2bf(v3.y); o1[6] = f2bf(v3.z); o1[7] = f2bf(v3.w);
      o2[0] = f2bf(v4.x); o2[1] = f2bf(v4.y); o2[2] = f2bf(v4.z); o2[3] = f2bf(v4.w);
      o2[4] = f2bf(v5.x); o2[5] = f2bf(v5.y); o2[6] = f2bf(v5.z); o2[7] = f2bf(v5.w);
      o3[0] = f2bf(v6.x); o3[1] = f2bf(v6.y); o3[2] = f2bf(v6.z); o3[3] = f2bf(v6.w);
      o3[4] = f2bf(v7.x); o3[5] = f2bf(v7.y); o3[6] = f2bf(v7.z); o3[7] = f2bf(v7.w);
      *(us8*)(adst + 0) = o0;
      *(us8*)(adst + 8) = o1;
      *(us8*)(adst + 16) = o2;
      *(us8*)(adst + 24) = o3;
    }
    __syncthreads();
#pragma unroll
    for (int kk = 0; kk < 2; kk++) {
      bf16x8 af[4];
#pragma unroll
      for (int mi = 0; mi < 4; mi++)
        af[mi] = ld_frag(sA + kk * 4096 + (wm * 64 + mi * 16 + l16) * 32 + quad * 8);
#pragma unroll
      for (int ni = 0; ni < 4; ni++) {
        bf16x8 bfr = ld_frag(sB + kk * 4096 + (wn * 64 + ni * 16 + l16) * 32 + quad * 8);
#pragma unroll
        for (int mi = 0; mi < 4; mi++) acc[mi][ni] = MFMA_BF16(af[mi], bfr, acc[mi][ni]);
      }
    }
  }

  if (mode < 2) {
    unsigned short* outp = (mode == 0) ? qh : kh;
#pragma unroll
    for (int mi = 0; mi < 4; mi++) {
#pragma unroll
      for (int ni = 0; ni < 4; ni++) {
        int c = wn * 64 + ni * 16 + l16;
        int h = h0 + (c >> 6), dk = c & 63;
        float bvv = bias[(dk << 4) + h];
        int mg0 = m0 + wm * 64 + mi * 16 + quad * 4;
#pragma unroll
        for (int r = 0; r < 4; r++) {
          int mg = mg0 + r;
          int bb = mg >> 11, s = mg & 2047;
          size_t dst = ((size_t)((bb << 4) + h) * SS + s) * DK + dk;
          outp[dst] = f2bf(acc[mi][ni][r] + bvv);
        }
      }
    }
  } else {
    // V: transpose through LDS so stores are contiguous in s
    __syncthreads();
#pragma unroll
    for (int mi = 0; mi < 4; mi++) {
#pragma unroll
      for (int ni = 0; ni < 4; ni++) {
        int c = wn * 64 + ni * 16 + l16;
        int h = h0 + (c >> 6), dk = c & 63;
        float bvv = bias[(dk << 4) + h];
        int ml0 = wm * 64 + mi * 16 + quad * 4;
#pragma unroll
        for (int r = 0; r < 4; r++)
          smem[c * 136 + ml0 + r] = f2bf(acc[mi][ni][r] + bvv);
      }
    }
    __syncthreads();
    int bb = m0 >> 11;
    int sbase = m0 & 2047;
#pragma unroll
    for (int i = 0; i < 8; i++) {
      int idx = tid + i * 256;  // 0..2047
      int c = idx >> 4, mc = (idx & 15) << 3;
      int h = h0 + (c >> 6), dk = c & 63;
      size_t dst = ((size_t)((bb << 4) + h) * DK + dk) * SS + sbase + mc;
      *(us8*)(vt + dst) = *(const us8*)(smem + c * 136 + mc);
    }
  }
}

// ---------------------------------------------------------------------------
// K2: causal flash attention. 128-row q-tiles, block y does tiles (y, 15-y)
// -> uniform 17 k-iterations. Grid x = bh so all 8 blocks of one (b,h) land
// on the SAME XCD (linear id = bh + 64*y -> id%8 = bh%8): K/V L2 locality.
// S^T = K*Q^T; P kept in registers (k-permuted PV, no sP LDS round-trip).
// LDS = sK(18K)+sV(17.4K) = 35 KB.
// ---------------------------------------------------------------------------
__global__ __launch_bounds__(256, 3) void attn(
    const unsigned short* __restrict__ qh, const unsigned short* __restrict__ kh,
    const unsigned short* __restrict__ vt, unsigned short* __restrict__ outc) {
  const int bh = blockIdx.x;  // 0..63  (fast dim -> XCD id = bh%8)
  const int by = blockIdx.y;  // 0..7   (pair index)
  const int b = bh >> 4, h = bh & 15;
  const unsigned short* Qp = qh + (size_t)bh * SS * DK;
  const unsigned short* Kp = kh + (size_t)bh * SS * DK;
  const unsigned short* Vp = vt + (size_t)bh * DK * SS;

  __shared__ unsigned short sK[128 * 72];   // [k_local][dk], pitch 72
  __shared__ unsigned short sV[64 * 136];   // [dk][k_local], pitch 136

  const int tid = threadIdx.x;
  const int lane = tid & 63;
  const int wave = tid >> 6;
  const int quad = lane >> 4, l16 = lane & 15;
  const int wq0 = wave * 32;  // wave's local q base

  const float sl = 0.125f * 1.44269504088896f;  // scale * log2(e), exp2 domain

  for (int pass = 0; pass < 2; pass++) {
    const int qt = pass ? (15 - by) : by;
    const int q0 = qt * 128;

    // Q fragments (B-operand of S^T mfma), lane l16 = q
    bf16x8 aq[2][2];
#pragma unroll
    for (int mi = 0; mi < 2; mi++)
#pragma unroll
      for (int kk = 0; kk < 2; kk++)
        aq[mi][kk] = ld_frag(Qp + (size_t)(q0 + wq0 + mi * 16 + l16) * DK + kk * 32 + quad * 8);

    f32x4 o_acc[2][4];
    float mrowL[2], lrowL[2];  // per-lane softmax state for q = l16 domain
#pragma unroll
    for (int mi = 0; mi < 2; mi++) {
#pragma unroll
      for (int ni = 0; ni < 4; ni++) o_acc[mi][ni] = f32x4{0.f, 0.f, 0.f, 0.f};
      mrowL[mi] = -1e30f;
      lrowL[mi] = 0.f;
    }

    for (int kt = 0; kt <= qt; kt++) {
      const int k0 = kt * 128;
      const bool diag = (kt == qt);
      __syncthreads();
#pragma unroll
      for (int i = 0; i < 4; i++) {
        int idx = tid + i * 256;
        int row = idx >> 3, c8 = (idx & 7) << 3;
        *(us8*)(sK + row * 72 + c8) = *(const us8*)(Kp + (size_t)(k0 + row) * DK + c8);
      }
#pragma unroll
      for (int i = 0; i < 4; i++) {
        int idx = tid + i * 256;
        int row = idx >> 4, cc = (idx & 15) << 3;
        *(us8*)(sV + row * 136 + cc) = *(const us8*)(Vp + (size_t)row * SS + k0 + cc);
      }
      __syncthreads();

      // S^T: sc[mi][kti] has col=l16=q, row k = kti*16 + quad*4 + r
      f32x4 sc[2][8];
#pragma unroll
      for (int mi = 0; mi < 2; mi++)
#pragma unroll
        for (int kti = 0; kti < 8; kti++) sc[mi][kti] = f32x4{0.f, 0.f, 0.f, 0.f};
#pragma unroll
      for (int kti = 0; kti < 8; kti++) {
#pragma unroll
        for (int kk = 0; kk < 2; kk++) {
          bf16x8 ak = ld_frag(sK + (kti * 16 + l16) * 72 + kk * 32 + quad * 8);
#pragma unroll
          for (int mi = 0; mi < 2; mi++) sc[mi][kti] = MFMA_BF16(ak, aq[mi][kk], sc[mi][kti]);
        }
      }

      // scale (exp2 domain); causal mask only on diagonal tile
      if (diag) {
#pragma unroll
        for (int mi = 0; mi < 2; mi++) {
          int ql = wq0 + mi * 16 + l16;  // local q
#pragma unroll
          for (int kti = 0; kti < 8; kti++)
#pragma unroll
            for (int r = 0; r < 4; r++) {
              int kl = kti * 16 + quad * 4 + r;
              float v = sc[mi][kti][r] * sl;
              sc[mi][kti][r] = (kl > ql) ? -1e30f : v;
            }
        }
      } else {
#pragma unroll
        for (int mi = 0; mi < 2; mi++)
#pragma unroll
          for (int kti = 0; kti < 8; kti++)
#pragma unroll
            for (int r = 0; r < 4; r++) sc[mi][kti][r] *= sl;
      }

      // online softmax: in-lane max over 32 k, reduce across the 4 quads
      float alphaL[2];
#pragma unroll
      for (int mi = 0; mi < 2; mi++) {
        f32x4 vm = sc[mi][0];
#pragma unroll
        for (int kti = 1; kti < 8; kti++)
#pragma unroll
          for (int r = 0; r < 4; r++) vm[r] = fmaxf(vm[r], sc[mi][kti][r]);
        float mx = fmaxf(fmaxf(vm[0], vm[1]), fmaxf(vm[2], vm[3]));
        mx = fmaxf(mx, __shfl_xor(mx, 16, 64));
        mx = fmaxf(mx, __shfl_xor(mx, 32, 64));
        float mnew = fmaxf(mrowL[mi], mx);
        alphaL[mi] = exp2f(mrowL[mi] - mnew);
        mrowL[mi] = mnew;
      }

      // per mi: rescale O, build packed P in regs, PV with permuted k-order:
      // chunk c: k_mfma(quad,j) = 32c + 16*(j>=4) + quad*4 + (j&3), same for A,B.
#pragma unroll
      for (int mi = 0; mi < 2; mi++) {
#pragma unroll
        for (int r = 0; r < 4; r++) {
          float a = __shfl(alphaL[mi], quad * 4 + r, 64);
#pragma unroll
          for (int ni = 0; ni < 4; ni++) o_acc[mi][ni][r] *= a;
        }
        us4 pk[8];
        f32x4 vs = f32x4{0.f, 0.f, 0.f, 0.f};
#pragma unroll
        for (int kti = 0; kti < 8; kti++) {
#pragma unroll
          for (int r = 0; r < 4; r++) {
            float p = exp2f(sc[mi][kti][r] - mrowL[mi]);
            vs[r] += p;
            pk[kti][r] = f2bf(p);
          }
        }
        float ls = (vs[0] + vs[1]) + (vs[2] + vs[3]);
        ls += __shfl_xor(ls, 16, 64);
        ls += __shfl_xor(ls, 32, 64);
        lrowL[mi] = lrowL[mi] * alphaL[mi] + ls;

#pragma unroll
        for (int c = 0; c < 4; c++) {
          bf16x8 ap = __builtin_bit_cast(
              bf16x8, __builtin_shufflevector(pk[2 * c], pk[2 * c + 1], 0, 1, 2, 3, 4, 5, 6, 7));
#pragma unroll
          for (int ni = 0; ni < 4; ni++) {
            const unsigned short* vb = sV + (ni * 16 + l16) * 136 + c * 32 + quad * 4;
            us4 lo = *(const us4*)vb;
            us4 hi = *(const us4*)(vb + 16);
            bf16x8 bfr = __builtin_bit_cast(
                bf16x8, __builtin_shufflevector(lo, hi, 0, 1, 2, 3, 4, 5, 6, 7));
            o_acc[mi][ni] = MFMA_BF16(ap, bfr, o_acc[mi][ni]);
          }
        }
      }
    }

    // epilogue: O/l -> concat layout channel h*64 + dk
#pragma unroll
    for (int mi = 0; mi < 2; mi++) {
#pragma unroll
      for (int r = 0; r < 4; r++) {
        float lr = __shfl(lrowL[mi], quad * 4 + r, 64);
        float inv = 1.0f / lr;
        int qg = q0 + wq0 + mi * 16 + quad * 4 + r;
        size_t rowbase = ((size_t)(b * SS + qg)) * DD + h * DK;
#pragma unroll
        for (int ni = 0; ni < 4; ni++) {
          int dk = ni * 16 + l16;
          outc[rowbase + dk] = f2bf(o_acc[mi][ni][r] * inv);
        }
      }
    }
    __syncthreads();  // protect sK/sV before second pass restages
  }
}

// ---------------------------------------------------------------------------
// K3: output projection. 128x128 tile, BK=64 two-half, both operands gl_lds.
// out[m,n] = sum_k AC[m,k] * Wo[n,k] + bo[n]  (fp32 out)
// ---------------------------------------------------------------------------
__global__ __launch_bounds__(256, 4) void out_proj(
    const unsigned short* __restrict__ ac, const unsigned short* __restrict__ wo,
    const float* __restrict__ bias, float* __restrict__ out) {
  const int m0 = blockIdx.x * 128;
  const int n0 = blockIdx.y * 128;
  __shared__ unsigned short sA[8192];  // [2][128*32]
  __shared__ unsigned short sB[8192];

  const int tid = threadIdx.x;
  const int lane = tid & 63;
  const int wave = tid >> 6;
  const int wm = wave & 1, wn = wave >> 1;
  const int quad = lane >> 4, l16 = lane & 15;

  f32x4 acc[4][4];
#pragma unroll
  for (int i = 0; i < 4; i++)
#pragma unroll
    for (int j = 0; j < 4; j++) acc[i][j] = f32x4{0.f, 0.f, 0.f, 0.f};

  for (int k0 = 0; k0 < DD; k0 += 64) {
    __syncthreads();
#pragma unroll
    for (int j = 0; j < 4; j++) {
      int cid = tid + j * 256;
      int half = cid >> 9;
      int rr = (cid & 511) >> 2;
      int c8 = (cid & 3) << 3;
      gl_lds16(ac + (size_t)(m0 + rr) * DD + k0 + half * 32 + c8,
               sA + half * 4096 + rr * 32 + c8);
    }
#pragma unroll
    for (int j = 0; j < 4; j++) {
      int cid = tid + j * 256;
      int half = cid >> 9;
      int rr = (cid & 511) >> 2;
      int c8 = (cid & 3) << 3;
      gl_lds16(wo + (size_t)(n0 + rr) * DD + k0 + half * 32 + c8,
               sB + half * 4096 + rr * 32 + c8);
    }
    __syncthreads();
#pragma unroll
    for (int kk = 0; kk < 2; kk++) {
      bf16x8 af[4];
#pragma unroll
      for (int mi = 0; mi < 4; mi++)
        af[mi] = ld_frag(sA + kk * 4096 + (wm * 64 + mi * 16 + l16) * 32 + quad * 8);
#pragma unroll
      for (int ni = 0; ni < 4; ni++) {
        bf16x8 bfr = ld_frag(sB + kk * 4096 + (wn * 64 + ni * 16 + l16) * 32 + quad * 8);
#pragma unroll
        for (int mi = 0; mi < 4; mi++) acc[mi][ni] = MFMA_BF16(af[mi], bfr, acc[mi][ni]);
      }
    }
  }

#pragma unroll
  for (int mi = 0; mi < 4; mi++) {
#pragma unroll
    for (int ni = 0; ni < 4; ni++) {
      int n = n0 + wn * 64 + ni * 16 + l16;
      float bvv = bias[n];
      int mg0 = m0 + wm * 64 + mi * 16 + quad * 4;
#pragma unroll
      for (int r = 0; r < 4; r++) out[(size_t)(mg0 + r) * DD + n] = acc[mi][ni][r] + bvv;
    }
  }
}

// ---------------------------------------------------------------------------
extern "C" void kernel_launch(void* const* d_in, const int* in_sizes, int n_in,
                              void* d_out, int out_size, void* d_ws, size_t ws_size,
                              hipStream_t stream) {
  const float* q_in = (const float*)d_in[0];
  const float* k_in = (const float*)d_in[1];
  const float* v_in = (const float*)d_in[2];
  // d_in[3] = mask: deterministic causal tril, handled analytically in attn()
  const float* w_q = (const float*)d_in[4];
  const float* b_q = (const float*)d_in[5];
  const float* w_k = (const float*)d_in[6];
  const float* b_k = (const float*)d_in[7];
  const float* w_v = (const float*)d_in[8];
  const float* b_v = (const float*)d_in[9];
  const float* w_o = (const float*)d_in[10];
  const float* b_o = (const float*)d_in[11];
  float* out = (float*)d_out;

  // ws layout (ushort elems), 36M = 72 MB:
  // wb[0,4M) | qh[4M,12M) | kh[12M,20M) | vt[20M,28M) | outc[28M,36M)
  unsigned short* ws = (unsigned short*)d_ws;
  unsigned short* wb = ws;
  unsigned short* qh = ws + (size_t)4 * 1024 * 1024;
  unsigned short* kh = ws + (size_t)12 * 1024 * 1024;
  unsigned short* vt = ws + (size_t)20 * 1024 * 1024;
  unsigned short* outc = ws + (size_t)28 * 1024 * 1024;

  const size_t WSZ = (size_t)DD * DD;

  cvt_weights<<<dim3(1024, 4), 256, 0, stream>>>(w_q, w_k, w_v, w_o, wb);
  qkv_gemm<<<dim3(64, 8, 3), 256, 0, stream>>>(q_in, k_in, v_in, wb, b_q, b_k, b_v, qh, kh, vt);
  attn<<<dim3(64, 8), 256, 0, stream>>>(qh, kh, vt, outc);
  out_proj<<<dim3(64, 8), 256, 0, stream>>>(outc, wb + 3 * WSZ, b_o, out);
}

// Round 6
// 374.600 us; speedup vs baseline: 1.5252x; 1.5252x over previous
//
#include <hip/hip_runtime.h>

// Problem: B=4, S=2048, D=1024, H=16, DK=64. Causal MHA forward, fp32 in/out.
#define BB 4
#define SS 2048
#define DD 1024
#define HH 16
#define DK 64
#define MM (BB * SS)  // 8192 tokens

typedef __bf16 bf16x8 __attribute__((ext_vector_type(8)));
typedef float f32x4 __attribute__((ext_vector_type(4)));
typedef unsigned short us8 __attribute__((ext_vector_type(8)));
typedef unsigned short us4 __attribute__((ext_vector_type(4)));

#define MFMA_BF16(a, b, c) __builtin_amdgcn_mfma_f32_16x16x32_bf16((a), (b), (c), 0, 0, 0)

__device__ __forceinline__ unsigned short f2bf(float f) {
  return __builtin_bit_cast(unsigned short, (__bf16)f);  // native cvt (RNE)
}

__device__ __forceinline__ bf16x8 ld_frag(const unsigned short* p) {
  return __builtin_bit_cast(bf16x8, *(const us8*)p);
}

// async global->LDS, 16B per lane. LDS dest must be wave-uniform base + lane*16.
__device__ __forceinline__ void gl_lds16(const unsigned short* g, unsigned short* l) {
  __builtin_amdgcn_global_load_lds((const __attribute__((address_space(1))) void*)g,
                                   (__attribute__((address_space(3))) void*)l, 16, 0, 0);
}

// ---------------------------------------------------------------------------
// K0: convert the 4 weight matrices fp32 -> bf16 (1M elems each)
// ---------------------------------------------------------------------------
__global__ void cvt_weights(const float* __restrict__ w0, const float* __restrict__ w1,
                            const float* __restrict__ w2, const float* __restrict__ w3,
                            unsigned short* __restrict__ dst) {
  const float* src = (blockIdx.y == 0) ? w0 : (blockIdx.y == 1) ? w1 : (blockIdx.y == 2) ? w2 : w3;
  unsigned short* d = dst + (size_t)blockIdx.y * (DD * DD);
  int idx = (blockIdx.x * 256 + threadIdx.x) * 4;
  float4 v = *(const float4*)(src + idx);
  us4 o;
  o[0] = f2bf(v.x); o[1] = f2bf(v.y); o[2] = f2bf(v.z); o[3] = f2bf(v.w);
  *(us4*)(d + idx) = o;
}

// ---------------------------------------------------------------------------
// K1: fused QKV projection, one dispatch (z = mode). Tile 128m x 128n (2 heads
// per n-tile, 8x X reuse, same-XCD stripe sharing). BK=64 as two 32-wide
// halves (m97 layout: unpadded stride-32 LDS, lane-linear for gl_lds).
// fp32 X converted in-register during A staging; bf16 W via global_load_lds.
// Column remap: block owns n-set {dk*16 + h : h in {h0,h0+1}, dk in 0..63}.
// mode 0/1 -> (B,H,S,DK); mode 2 -> V^T (B,H,DK,S) via LDS transpose.
// ---------------------------------------------------------------------------
__global__ __launch_bounds__(256, 4) void qkv_gemm(
    const float* __restrict__ xq, const float* __restrict__ xk, const float* __restrict__ xv,
    const unsigned short* __restrict__ wb,
    const float* __restrict__ bq, const float* __restrict__ bk, const float* __restrict__ bv,
    unsigned short* __restrict__ qh, unsigned short* __restrict__ kh,
    unsigned short* __restrict__ vt) {
  const int mode = blockIdx.z;
  const float* x = (mode == 0) ? xq : (mode == 1) ? xk : xv;
  const unsigned short* w = wb + (size_t)mode * (DD * DD);
  const float* bias = (mode == 0) ? bq : (mode == 1) ? bk : bv;

  const int m0 = blockIdx.x * 128;
  const int h0 = blockIdx.y * 2;

  // sA[2][128*32] | sB[2][128*32]; V epilogue reuses as sT[128*136] (17408)
  __shared__ unsigned short smem[17408];
  unsigned short* sA = smem;
  unsigned short* sB = smem + 8192;

  const int tid = threadIdx.x;
  const int lane = tid & 63;
  const int wave = tid >> 6;
  const int wm = wave & 1, wn = wave >> 1;
  const int quad = lane >> 4, l16 = lane & 15;

  f32x4 acc[4][4];
#pragma unroll
  for (int i = 0; i < 4; i++)
#pragma unroll
    for (int j = 0; j < 4; j++) acc[i][j] = f32x4{0.f, 0.f, 0.f, 0.f};

  // A staging: thread owns row tid>>1, half tid&1 (cols half*32..+31)
  const int arow = tid >> 1, ahalf = tid & 1;
  const float* ag = x + (size_t)(m0 + arow) * DD + ahalf * 32;
  unsigned short* adst = sA + ahalf * 4096 + arow * 32;

  for (int k0 = 0; k0 < DD; k0 += 64) {
    __syncthreads();
    // stage B: 128 rows x 64 cols bf16, 4 lane-linear gl_lds calls
#pragma unroll
    for (int j = 0; j < 4; j++) {
      int cid = tid + j * 256;            // 0..1023
      int half = cid >> 9;                // 0/1 -> cols k0+half*32
      int rr = (cid & 511) >> 2;          // 0..127
      int c8 = (cid & 3) << 3;
      int n = ((rr & 63) << 4) + h0 + (rr >> 6);
      gl_lds16(w + (size_t)n * DD + k0 + half * 32 + c8,
               sB + half * 4096 + rr * 32 + c8);
    }
    // stage A: fp32 -> bf16 in regs -> 4 b128 writes (full 32-elem half-row)
    {
      const float* a = ag + k0;
      float4 v0 = *(const float4*)(a + 0);
      float4 v1 = *(const float4*)(a + 4);
      float4 v2 = *(const float4*)(a + 8);
      float4 v3 = *(const float4*)(a + 12);
      float4 v4 = *(const float4*)(a + 16);
      float4 v5 = *(const float4*)(a + 20);
      float4 v6 = *(const float4*)(a + 24);
      float4 v7 = *(const float4*)(a + 28);
      us8 o0, o1, o2, o3;
      o0[0] = f2bf(v0.x); o0[1] = f2bf(v0.y); o0[2] = f2bf(v0.z); o0[3] = f2bf(v0.w);
      o0[4] = f2bf(v1.x); o0[5] = f2bf(v1.y); o0[6] = f2bf(v1.z); o0[7] = f2bf(v1.w);
      o1[0] = f2bf(v2.x); o1[1] = f2bf(v2.y); o1[2] = f2bf(v2.z); o1[3] = f2bf(v2.w);
      o1[4] = f2bf(v3.x); o1[5] = f2bf(v3.y); o1[6] = f2bf(v3.z); o1[7] = f2bf(v3.w);
      o2[0] = f2bf(v4.x); o2[1] = f2bf(v4.y); o2[2] = f2bf(v4.z); o2[3] = f2bf(v4.w);
      o2[4] = f2bf(v5.x); o2[5] = f2bf(v5.y); o2[6] = f2bf(v5.z); o2[7] = f2bf(v5.w);
      o3[0] = f2bf(v6.x); o3[1] = f2bf(v6.y); o3[2] = f2bf(v6.z); o3[3] = f2bf(v6.w);
      o3[4] = f2bf(v7.x); o3[5] = f2bf(v7.y); o3[6] = f2bf(v7.z); o3[7] = f2bf(v7.w);
      *(us8*)(adst + 0) = o0;
      *(us8*)(adst + 8) = o1;
      *(us8*)(adst + 16) = o2;
      *(us8*)(adst + 24) = o3;
    }
    __syncthreads();
#pragma unroll
    for (int kk = 0; kk < 2; kk++) {
      bf16x8 af[4];
#pragma unroll
      for (int mi = 0; mi < 4; mi++)
        af[mi] = ld_frag(sA + kk * 4096 + (wm * 64 + mi * 16 + l16) * 32 + quad * 8);
#pragma unroll
      for (int ni = 0; ni < 4; ni++) {
        bf16x8 bfr = ld_frag(sB + kk * 4096 + (wn * 64 + ni * 16 + l16) * 32 + quad * 8);
#pragma unroll
        for (int mi = 0; mi < 4; mi++) acc[mi][ni] = MFMA_BF16(af[mi], bfr, acc[mi][ni]);
      }
    }
  }

  if (mode < 2) {
    unsigned short* outp = (mode == 0) ? qh : kh;
#pragma unroll
    for (int mi = 0; mi < 4; mi++) {
#pragma unroll
      for (int ni = 0; ni < 4; ni++) {
        int c = wn * 64 + ni * 16 + l16;
        int h = h0 + (c >> 6), dk = c & 63;
        float bvv = bias[(dk << 4) + h];
        int mg0 = m0 + wm * 64 + mi * 16 + quad * 4;
#pragma unroll
        for (int r = 0; r < 4; r++) {
          int mg = mg0 + r;
          int bb = mg >> 11, s = mg & 2047;
          size_t dst = ((size_t)((bb << 4) + h) * SS + s) * DK + dk;
          outp[dst] = f2bf(acc[mi][ni][r] + bvv);
        }
      }
    }
  } else {
    // V: transpose through LDS so stores are contiguous in s
    __syncthreads();
#pragma unroll
    for (int mi = 0; mi < 4; mi++) {
#pragma unroll
      for (int ni = 0; ni < 4; ni++) {
        int c = wn * 64 + ni * 16 + l16;
        int h = h0 + (c >> 6), dk = c & 63;
        float bvv = bias[(dk << 4) + h];
        int ml0 = wm * 64 + mi * 16 + quad * 4;
#pragma unroll
        for (int r = 0; r < 4; r++)
          smem[c * 136 + ml0 + r] = f2bf(acc[mi][ni][r] + bvv);
      }
    }
    __syncthreads();
    int bb = m0 >> 11;
    int sbase = m0 & 2047;
#pragma unroll
    for (int i = 0; i < 8; i++) {
      int idx = tid + i * 256;  // 0..2047
      int c = idx >> 4, mc = (idx & 15) << 3;
      int h = h0 + (c >> 6), dk = c & 63;
      size_t dst = ((size_t)((bb << 4) + h) * DK + dk) * SS + sbase + mc;
      *(us8*)(vt + dst) = *(const us8*)(smem + c * 136 + mc);
    }
  }
}

// ---------------------------------------------------------------------------
// K2: causal flash attention. 128-row q-tiles, block y does tiles (y, 15-y)
// -> uniform 17 k-iterations. Grid x = bh so all 8 blocks of one (b,h) land
// on the SAME XCD (linear id = bh + 64*y -> id%8 = bh%8): K/V L2 locality.
// S^T = K*Q^T; P kept in registers (k-permuted PV, no sP LDS round-trip).
// LDS = sK(18K)+sV(17.4K) = 35 KB.
// __launch_bounds__(256,2): (256,3) capped VGPRs at ~170 and spilled sc[2][8]
// to scratch -> 1.1 GB of HBM spill traffic (R5 post-mortem). Do not raise.
// ---------------------------------------------------------------------------
__global__ __launch_bounds__(256, 2) void attn(
    const unsigned short* __restrict__ qh, const unsigned short* __restrict__ kh,
    const unsigned short* __restrict__ vt, unsigned short* __restrict__ outc) {
  const int bh = blockIdx.x;  // 0..63  (fast dim -> XCD id = bh%8)
  const int by = blockIdx.y;  // 0..7   (pair index)
  const int b = bh >> 4, h = bh & 15;
  const unsigned short* Qp = qh + (size_t)bh * SS * DK;
  const unsigned short* Kp = kh + (size_t)bh * SS * DK;
  const unsigned short* Vp = vt + (size_t)bh * DK * SS;

  __shared__ unsigned short sK[128 * 72];   // [k_local][dk], pitch 72
  __shared__ unsigned short sV[64 * 136];   // [dk][k_local], pitch 136

  const int tid = threadIdx.x;
  const int lane = tid & 63;
  const int wave = tid >> 6;
  const int quad = lane >> 4, l16 = lane & 15;
  const int wq0 = wave * 32;  // wave's local q base

  const float sl = 0.125f * 1.44269504088896f;  // scale * log2(e), exp2 domain

  for (int pass = 0; pass < 2; pass++) {
    const int qt = pass ? (15 - by) : by;
    const int q0 = qt * 128;

    // Q fragments (B-operand of S^T mfma), lane l16 = q
    bf16x8 aq[2][2];
#pragma unroll
    for (int mi = 0; mi < 2; mi++)
#pragma unroll
      for (int kk = 0; kk < 2; kk++)
        aq[mi][kk] = ld_frag(Qp + (size_t)(q0 + wq0 + mi * 16 + l16) * DK + kk * 32 + quad * 8);

    f32x4 o_acc[2][4];
    float mrowL[2], lrowL[2];  // per-lane softmax state for q = l16 domain
#pragma unroll
    for (int mi = 0; mi < 2; mi++) {
#pragma unroll
      for (int ni = 0; ni < 4; ni++) o_acc[mi][ni] = f32x4{0.f, 0.f, 0.f, 0.f};
      mrowL[mi] = -1e30f;
      lrowL[mi] = 0.f;
    }

    for (int kt = 0; kt <= qt; kt++) {
      const int k0 = kt * 128;
      const bool diag = (kt == qt);
      __syncthreads();
#pragma unroll
      for (int i = 0; i < 4; i++) {
        int idx = tid + i * 256;
        int row = idx >> 3, c8 = (idx & 7) << 3;
        *(us8*)(sK + row * 72 + c8) = *(const us8*)(Kp + (size_t)(k0 + row) * DK + c8);
      }
#pragma unroll
      for (int i = 0; i < 4; i++) {
        int idx = tid + i * 256;
        int row = idx >> 4, cc = (idx & 15) << 3;
        *(us8*)(sV + row * 136 + cc) = *(const us8*)(Vp + (size_t)row * SS + k0 + cc);
      }
      __syncthreads();

      // S^T: sc[mi][kti] has col=l16=q, row k = kti*16 + quad*4 + r
      f32x4 sc[2][8];
#pragma unroll
      for (int mi = 0; mi < 2; mi++)
#pragma unroll
        for (int kti = 0; kti < 8; kti++) sc[mi][kti] = f32x4{0.f, 0.f, 0.f, 0.f};
#pragma unroll
      for (int kti = 0; kti < 8; kti++) {
#pragma unroll
        for (int kk = 0; kk < 2; kk++) {
          bf16x8 ak = ld_frag(sK + (kti * 16 + l16) * 72 + kk * 32 + quad * 8);
#pragma unroll
          for (int mi = 0; mi < 2; mi++) sc[mi][kti] = MFMA_BF16(ak, aq[mi][kk], sc[mi][kti]);
        }
      }

      // scale (exp2 domain); causal mask only on diagonal tile
      if (diag) {
#pragma unroll
        for (int mi = 0; mi < 2; mi++) {
          int ql = wq0 + mi * 16 + l16;  // local q
#pragma unroll
          for (int kti = 0; kti < 8; kti++)
#pragma unroll
            for (int r = 0; r < 4; r++) {
              int kl = kti * 16 + quad * 4 + r;
              float v = sc[mi][kti][r] * sl;
              sc[mi][kti][r] = (kl > ql) ? -1e30f : v;
            }
        }
      } else {
#pragma unroll
        for (int mi = 0; mi < 2; mi++)
#pragma unroll
          for (int kti = 0; kti < 8; kti++)
#pragma unroll
            for (int r = 0; r < 4; r++) sc[mi][kti][r] *= sl;
      }

      // online softmax: in-lane max over 32 k, reduce across the 4 quads
      float alphaL[2];
#pragma unroll
      for (int mi = 0; mi < 2; mi++) {
        f32x4 vm = sc[mi][0];
#pragma unroll
        for (int kti = 1; kti < 8; kti++)
#pragma unroll
          for (int r = 0; r < 4; r++) vm[r] = fmaxf(vm[r], sc[mi][kti][r]);
        float mx = fmaxf(fmaxf(vm[0], vm[1]), fmaxf(vm[2], vm[3]));
        mx = fmaxf(mx, __shfl_xor(mx, 16, 64));
        mx = fmaxf(mx, __shfl_xor(mx, 32, 64));
        float mnew = fmaxf(mrowL[mi], mx);
        alphaL[mi] = exp2f(mrowL[mi] - mnew);
        mrowL[mi] = mnew;
      }

      // per mi: rescale O, build packed P in regs, PV with permuted k-order:
      // chunk c: k_mfma(quad,j) = 32c + 16*(j>=4) + quad*4 + (j&3), same for A,B.
#pragma unroll
      for (int mi = 0; mi < 2; mi++) {
#pragma unroll
        for (int r = 0; r < 4; r++) {
          float a = __shfl(alphaL[mi], quad * 4 + r, 64);
#pragma unroll
          for (int ni = 0; ni < 4; ni++) o_acc[mi][ni][r] *= a;
        }
        us4 pk[8];
        f32x4 vs = f32x4{0.f, 0.f, 0.f, 0.f};
#pragma unroll
        for (int kti = 0; kti < 8; kti++) {
#pragma unroll
          for (int r = 0; r < 4; r++) {
            float p = exp2f(sc[mi][kti][r] - mrowL[mi]);
            vs[r] += p;
            pk[kti][r] = f2bf(p);
          }
        }
        float ls = (vs[0] + vs[1]) + (vs[2] + vs[3]);
        ls += __shfl_xor(ls, 16, 64);
        ls += __shfl_xor(ls, 32, 64);
        lrowL[mi] = lrowL[mi] * alphaL[mi] + ls;

#pragma unroll
        for (int c = 0; c < 4; c++) {
          bf16x8 ap = __builtin_bit_cast(
              bf16x8, __builtin_shufflevector(pk[2 * c], pk[2 * c + 1], 0, 1, 2, 3, 4, 5, 6, 7));
#pragma unroll
          for (int ni = 0; ni < 4; ni++) {
            const unsigned short* vb = sV + (ni * 16 + l16) * 136 + c * 32 + quad * 4;
            us4 lo = *(const us4*)vb;
            us4 hi = *(const us4*)(vb + 16);
            bf16x8 bfr = __builtin_bit_cast(
                bf16x8, __builtin_shufflevector(lo, hi, 0, 1, 2, 3, 4, 5, 6, 7));
            o_acc[mi][ni] = MFMA_BF16(ap, bfr, o_acc[mi][ni]);
          }
        }
      }
    }

    // epilogue: O/l -> concat layout channel h*64 + dk
#pragma unroll
    for (int mi = 0; mi < 2; mi++) {
#pragma unroll
      for (int r = 0; r < 4; r++) {
        float lr = __shfl(lrowL[mi], quad * 4 + r, 64);
        float inv = 1.0f / lr;
        int qg = q0 + wq0 + mi * 16 + quad * 4 + r;
        size_t rowbase = ((size_t)(b * SS + qg)) * DD + h * DK;
#pragma unroll
        for (int ni = 0; ni < 4; ni++) {
          int dk = ni * 16 + l16;
          outc[rowbase + dk] = f2bf(o_acc[mi][ni][r] * inv);
        }
      }
    }
    __syncthreads();  // protect sK/sV before second pass restages
  }
}

// ---------------------------------------------------------------------------
// K3: output projection. 128x128 tile, BK=64 two-half, both operands gl_lds.
// out[m,n] = sum_k AC[m,k] * Wo[n,k] + bo[n]  (fp32 out)
// ---------------------------------------------------------------------------
__global__ __launch_bounds__(256, 4) void out_proj(
    const unsigned short* __restrict__ ac, const unsigned short* __restrict__ wo,
    const float* __restrict__ bias, float* __restrict__ out) {
  const int m0 = blockIdx.x * 128;
  const int n0 = blockIdx.y * 128;
  __shared__ unsigned short sA[8192];  // [2][128*32]
  __shared__ unsigned short sB[8192];

  const int tid = threadIdx.x;
  const int lane = tid & 63;
  const int wave = tid >> 6;
  const int wm = wave & 1, wn = wave >> 1;
  const int quad = lane >> 4, l16 = lane & 15;

  f32x4 acc[4][4];
#pragma unroll
  for (int i = 0; i < 4; i++)
#pragma unroll
    for (int j = 0; j < 4; j++) acc[i][j] = f32x4{0.f, 0.f, 0.f, 0.f};

  for (int k0 = 0; k0 < DD; k0 += 64) {
    __syncthreads();
#pragma unroll
    for (int j = 0; j < 4; j++) {
      int cid = tid + j * 256;
      int half = cid >> 9;
      int rr = (cid & 511) >> 2;
      int c8 = (cid & 3) << 3;
      gl_lds16(ac + (size_t)(m0 + rr) * DD + k0 + half * 32 + c8,
               sA + half * 4096 + rr * 32 + c8);
    }
#pragma unroll
    for (int j = 0; j < 4; j++) {
      int cid = tid + j * 256;
      int half = cid >> 9;
      int rr = (cid & 511) >> 2;
      int c8 = (cid & 3) << 3;
      gl_lds16(wo + (size_t)(n0 + rr) * DD + k0 + half * 32 + c8,
               sB + half * 4096 + rr * 32 + c8);
    }
    __syncthreads();
#pragma unroll
    for (int kk = 0; kk < 2; kk++) {
      bf16x8 af[4];
#pragma unroll
      for (int mi = 0; mi < 4; mi++)
        af[mi] = ld_frag(sA + kk * 4096 + (wm * 64 + mi * 16 + l16) * 32 + quad * 8);
#pragma unroll
      for (int ni = 0; ni < 4; ni++) {
        bf16x8 bfr = ld_frag(sB + kk * 4096 + (wn * 64 + ni * 16 + l16) * 32 + quad * 8);
#pragma unroll
        for (int mi = 0; mi < 4; mi++) acc[mi][ni] = MFMA_BF16(af[mi], bfr, acc[mi][ni]);
      }
    }
  }

#pragma unroll
  for (int mi = 0; mi < 4; mi++) {
#pragma unroll
    for (int ni = 0; ni < 4; ni++) {
      int n = n0 + wn * 64 + ni * 16 + l16;
      float bvv = bias[n];
      int mg0 = m0 + wm * 64 + mi * 16 + quad * 4;
#pragma unroll
      for (int r = 0; r < 4; r++) out[(size_t)(mg0 + r) * DD + n] = acc[mi][ni][r] + bvv;
    }
  }
}

// ---------------------------------------------------------------------------
extern "C" void kernel_launch(void* const* d_in, const int* in_sizes, int n_in,
                              void* d_out, int out_size, void* d_ws, size_t ws_size,
                              hipStream_t stream) {
  const float* q_in = (const float*)d_in[0];
  const float* k_in = (const float*)d_in[1];
  const float* v_in = (const float*)d_in[2];
  // d_in[3] = mask: deterministic causal tril, handled analytically in attn()
  const float* w_q = (const float*)d_in[4];
  const float* b_q = (const float*)d_in[5];
  const float* w_k = (const float*)d_in[6];
  const float* b_k = (const float*)d_in[7];
  const float* w_v = (const float*)d_in[8];
  const float* b_v = (const float*)d_in[9];
  const float* w_o = (const float*)d_in[10];
  const float* b_o = (const float*)d_in[11];
  float* out = (float*)d_out;

  // ws layout (ushort elems), 36M = 72 MB:
  // wb[0,4M) | qh[4M,12M) | kh[12M,20M) | vt[20M,28M) | outc[28M,36M)
  unsigned short* ws = (unsigned short*)d_ws;
  unsigned short* wb = ws;
  unsigned short* qh = ws + (size_t)4 * 1024 * 1024;
  unsigned short* kh = ws + (size_t)12 * 1024 * 1024;
  unsigned short* vt = ws + (size_t)20 * 1024 * 1024;
  unsigned short* outc = ws + (size_t)28 * 1024 * 1024;

  const size_t WSZ = (size_t)DD * DD;

  cvt_weights<<<dim3(1024, 4), 256, 0, stream>>>(w_q, w_k, w_v, w_o, wb);
  qkv_gemm<<<dim3(64, 8, 3), 256, 0, stream>>>(q_in, k_in, v_in, wb, b_q, b_k, b_v, qh, kh, vt);
  attn<<<dim3(64, 8), 256, 0, stream>>>(qh, kh, vt, outc);
  out_proj<<<dim3(64, 8), 256, 0, stream>>>(outc, wb + 3 * WSZ, b_o, out);
}

// Round 7
// 370.818 us; speedup vs baseline: 1.5408x; 1.0102x over previous
//
#include <hip/hip_runtime.h>

// Problem: B=4, S=2048, D=1024, H=16, DK=64. Causal MHA forward, fp32 in/out.
#define BB 4
#define SS 2048
#define DD 1024
#define HH 16
#define DK 64
#define MM (BB * SS)  // 8192 tokens

typedef __bf16 bf16x8 __attribute__((ext_vector_type(8)));
typedef float f32x4 __attribute__((ext_vector_type(4)));
typedef unsigned short us8 __attribute__((ext_vector_type(8)));
typedef unsigned short us4 __attribute__((ext_vector_type(4)));

#define MFMA_BF16(a, b, c) __builtin_amdgcn_mfma_f32_16x16x32_bf16((a), (b), (c), 0, 0, 0)

__device__ __forceinline__ unsigned short f2bf(float f) {
  return __builtin_bit_cast(unsigned short, (__bf16)f);  // native cvt (RNE)
}

__device__ __forceinline__ bf16x8 ld_frag(const unsigned short* p) {
  return __builtin_bit_cast(bf16x8, *(const us8*)p);
}

// async global->LDS, 16B per lane. LDS dest must be wave-uniform base + lane*16.
__device__ __forceinline__ void gl_lds16(const unsigned short* g, unsigned short* l) {
  __builtin_amdgcn_global_load_lds((const __attribute__((address_space(1))) void*)g,
                                   (__attribute__((address_space(3))) void*)l, 16, 0, 0);
}

// ---------------------------------------------------------------------------
// K0: convert the 4 weight matrices fp32 -> bf16 (1M elems each)
// ---------------------------------------------------------------------------
__global__ void cvt_weights(const float* __restrict__ w0, const float* __restrict__ w1,
                            const float* __restrict__ w2, const float* __restrict__ w3,
                            unsigned short* __restrict__ dst) {
  const float* src = (blockIdx.y == 0) ? w0 : (blockIdx.y == 1) ? w1 : (blockIdx.y == 2) ? w2 : w3;
  unsigned short* d = dst + (size_t)blockIdx.y * (DD * DD);
  int idx = (blockIdx.x * 256 + threadIdx.x) * 4;
  float4 v = *(const float4*)(src + idx);
  us4 o;
  o[0] = f2bf(v.x); o[1] = f2bf(v.y); o[2] = f2bf(v.z); o[3] = f2bf(v.w);
  *(us4*)(d + idx) = o;
}

// ---------------------------------------------------------------------------
// K1: fused QKV projection, one dispatch (z = mode). Tile 128m x 128n, BK=64
// (two 32-wide halves). Register-prefetch pipeline: iter k+1's A (fp32) and B
// (bf16) are loaded to VGPRs right after the staging barrier of iter k, so
// they overlap the whole MFMA phase; LDS writes come from registers (no
// gl_lds in-loop sync). A chunks are XOR-swizzled (c ^ ((row>>1)&3)) so the
// ds_write_b128 wave pattern covers all 32 banks (R6: unswizzled = 8 banks,
// 4x serialize, ~10M conflict cycles). B LDS writes are lane-linear (conflict
// free). Column remap: block owns {dk*16+h : h in {h0,h0+1}, dk in 0..63}.
// mode 0/1 -> (B,H,S,DK); mode 2 -> V^T (B,H,DK,S) via LDS transpose.
// __launch_bounds__(256,3): ~150 VGPRs live (acc 64 + prefetch 48 + frags);
// (256,4) caps at 128 and would spill to scratch (R5 post-mortem lesson).
// ---------------------------------------------------------------------------
__global__ __launch_bounds__(256, 3) void qkv_gemm(
    const float* __restrict__ xq, const float* __restrict__ xk, const float* __restrict__ xv,
    const unsigned short* __restrict__ wb,
    const float* __restrict__ bq, const float* __restrict__ bk, const float* __restrict__ bv,
    unsigned short* __restrict__ qh, unsigned short* __restrict__ kh,
    unsigned short* __restrict__ vt) {
  const int mode = blockIdx.z;
  const float* x = (mode == 0) ? xq : (mode == 1) ? xk : xv;
  const unsigned short* w = wb + (size_t)mode * (DD * DD);
  const float* bias = (mode == 0) ? bq : (mode == 1) ? bk : bv;

  const int m0 = blockIdx.x * 128;
  const int h0 = blockIdx.y * 2;

  // sA[2][128*32] | sB[2][128*32]; V epilogue reuses as sT[128*136] (17408)
  __shared__ unsigned short smem[17408];
  unsigned short* sA = smem;
  unsigned short* sB = smem + 8192;

  const int tid = threadIdx.x;
  const int lane = tid & 63;
  const int wave = tid >> 6;
  const int wm = wave & 1, wn = wave >> 1;
  const int quad = lane >> 4, l16 = lane & 15;

  f32x4 acc[4][4];
#pragma unroll
  for (int i = 0; i < 4; i++)
#pragma unroll
    for (int j = 0; j < 4; j++) acc[i][j] = f32x4{0.f, 0.f, 0.f, 0.f};

  // A: thread owns row tid>>1 (128 fp32 = 32 cols), half tid&1.
  const int arow = tid >> 1, ahalf = tid & 1;
  const float* ag = x + (size_t)(m0 + arow) * DD + ahalf * 32;
  unsigned short* arow_base = sA + ahalf * 4096 + arow * 32;
  const int asw = (arow >> 1) & 3;  // chunk swizzle for this row

  // B: thread owns 4 16B chunks, cid = tid + j*256 (lane-linear per j).
  const unsigned short* bsrc[4];
  unsigned short* bdst[4];
#pragma unroll
  for (int j = 0; j < 4; j++) {
    int cid = tid + j * 256;
    int half = cid >> 9, rr = (cid & 511) >> 2, c8 = (cid & 3) << 3;
    int n = ((rr & 63) << 4) + h0 + (rr >> 6);
    bsrc[j] = w + (size_t)n * DD + half * 32 + c8;
    bdst[j] = sB + half * 4096 + rr * 32 + c8;
  }

  // prologue: load k0=0 into regs
  float4 va[8];
  us8 vbr[4];
#pragma unroll
  for (int i = 0; i < 8; i++) va[i] = *(const float4*)(ag + 0 + i * 4);
#pragma unroll
  for (int j = 0; j < 4; j++) vbr[j] = *(const us8*)(bsrc[j] + 0);

  for (int k0 = 0; k0 < DD; k0 += 64) {
    __syncthreads();  // previous compute done reading LDS
    // store A (cvt fp32->bf16, swizzled chunks) and B (lane-linear) from regs
#pragma unroll
    for (int c = 0; c < 4; c++) {
      us8 o;
      o[0] = f2bf(va[2 * c].x); o[1] = f2bf(va[2 * c].y);
      o[2] = f2bf(va[2 * c].z); o[3] = f2bf(va[2 * c].w);
      o[4] = f2bf(va[2 * c + 1].x); o[5] = f2bf(va[2 * c + 1].y);
      o[6] = f2bf(va[2 * c + 1].z); o[7] = f2bf(va[2 * c + 1].w);
      *(us8*)(arow_base + ((c ^ asw) << 3)) = o;
    }
#pragma unroll
    for (int j = 0; j < 4; j++) *(us8*)(bdst[j]) = vbr[j];
    __syncthreads();  // tile visible to all waves

    // prefetch next tile into regs (overlaps the MFMA phase below; the
    // compiler's vmcnt(0) drain at the next barrier is exactly the use point)
    if (k0 + 64 < DD) {
#pragma unroll
      for (int i = 0; i < 8; i++) va[i] = *(const float4*)(ag + k0 + 64 + i * 4);
#pragma unroll
      for (int j = 0; j < 4; j++) vbr[j] = *(const us8*)(bsrc[j] + k0 + 64);
    }

#pragma unroll
    for (int kk = 0; kk < 2; kk++) {
      bf16x8 af[4];
#pragma unroll
      for (int mi = 0; mi < 4; mi++) {
        int row = wm * 64 + mi * 16 + l16;
        af[mi] = ld_frag(sA + kk * 4096 + row * 32 + ((quad ^ ((row >> 1) & 3)) << 3));
      }
#pragma unroll
      for (int ni = 0; ni < 4; ni++) {
        bf16x8 bfr = ld_frag(sB + kk * 4096 + (wn * 64 + ni * 16 + l16) * 32 + quad * 8);
#pragma unroll
        for (int mi = 0; mi < 4; mi++) acc[mi][ni] = MFMA_BF16(af[mi], bfr, acc[mi][ni]);
      }
    }
  }

  if (mode < 2) {
    unsigned short* outp = (mode == 0) ? qh : kh;
#pragma unroll
    for (int mi = 0; mi < 4; mi++) {
#pragma unroll
      for (int ni = 0; ni < 4; ni++) {
        int c = wn * 64 + ni * 16 + l16;
        int h = h0 + (c >> 6), dk = c & 63;
        float bvv = bias[(dk << 4) + h];
        int mg0 = m0 + wm * 64 + mi * 16 + quad * 4;
#pragma unroll
        for (int r = 0; r < 4; r++) {
          int mg = mg0 + r;
          int bb = mg >> 11, s = mg & 2047;
          size_t dst = ((size_t)((bb << 4) + h) * SS + s) * DK + dk;
          outp[dst] = f2bf(acc[mi][ni][r] + bvv);
        }
      }
    }
  } else {
    // V: transpose through LDS so stores are contiguous in s
    __syncthreads();
#pragma unroll
    for (int mi = 0; mi < 4; mi++) {
#pragma unroll
      for (int ni = 0; ni < 4; ni++) {
        int c = wn * 64 + ni * 16 + l16;
        int h = h0 + (c >> 6), dk = c & 63;
        float bvv = bias[(dk << 4) + h];
        int ml0 = wm * 64 + mi * 16 + quad * 4;
#pragma unroll
        for (int r = 0; r < 4; r++)
          smem[c * 136 + ml0 + r] = f2bf(acc[mi][ni][r] + bvv);
      }
    }
    __syncthreads();
    int bb = m0 >> 11;
    int sbase = m0 & 2047;
#pragma unroll
    for (int i = 0; i < 8; i++) {
      int idx = tid + i * 256;  // 0..2047
      int c = idx >> 4, mc = (idx & 15) << 3;
      int h = h0 + (c >> 6), dk = c & 63;
      size_t dst = ((size_t)((bb << 4) + h) * DK + dk) * SS + sbase + mc;
      *(us8*)(vt + dst) = *(const us8*)(smem + c * 136 + mc);
    }
  }
}

// ---------------------------------------------------------------------------
// K2: causal flash attention. 128-row q-tiles, block y does tiles (y, 15-y)
// -> uniform 17 k-iterations. Grid x = bh so all 8 blocks of one (b,h) land
// on the SAME XCD (linear id = bh + 64*y -> id%8 = bh%8): K/V L2 locality.
// S^T = K*Q^T; P kept in registers (k-permuted PV, no sP LDS round-trip).
// LDS = sK(18K)+sV(17.4K) = 35 KB.
// __launch_bounds__(256,2): (256,3) capped VGPRs at ~170 and spilled sc[2][8]
// to scratch -> 1.1 GB of HBM spill traffic (R5 post-mortem). Do not raise.
// ---------------------------------------------------------------------------
__global__ __launch_bounds__(256, 2) void attn(
    const unsigned short* __restrict__ qh, const unsigned short* __restrict__ kh,
    const unsigned short* __restrict__ vt, unsigned short* __restrict__ outc) {
  const int bh = blockIdx.x;  // 0..63  (fast dim -> XCD id = bh%8)
  const int by = blockIdx.y;  // 0..7   (pair index)
  const int b = bh >> 4, h = bh & 15;
  const unsigned short* Qp = qh + (size_t)bh * SS * DK;
  const unsigned short* Kp = kh + (size_t)bh * SS * DK;
  const unsigned short* Vp = vt + (size_t)bh * DK * SS;

  __shared__ unsigned short sK[128 * 72];   // [k_local][dk], pitch 72
  __shared__ unsigned short sV[64 * 136];   // [dk][k_local], pitch 136

  const int tid = threadIdx.x;
  const int lane = tid & 63;
  const int wave = tid >> 6;
  const int quad = lane >> 4, l16 = lane & 15;
  const int wq0 = wave * 32;  // wave's local q base

  const float sl = 0.125f * 1.44269504088896f;  // scale * log2(e), exp2 domain

  for (int pass = 0; pass < 2; pass++) {
    const int qt = pass ? (15 - by) : by;
    const int q0 = qt * 128;

    // Q fragments (B-operand of S^T mfma), lane l16 = q
    bf16x8 aq[2][2];
#pragma unroll
    for (int mi = 0; mi < 2; mi++)
#pragma unroll
      for (int kk = 0; kk < 2; kk++)
        aq[mi][kk] = ld_frag(Qp + (size_t)(q0 + wq0 + mi * 16 + l16) * DK + kk * 32 + quad * 8);

    f32x4 o_acc[2][4];
    float mrowL[2], lrowL[2];  // per-lane softmax state for q = l16 domain
#pragma unroll
    for (int mi = 0; mi < 2; mi++) {
#pragma unroll
      for (int ni = 0; ni < 4; ni++) o_acc[mi][ni] = f32x4{0.f, 0.f, 0.f, 0.f};
      mrowL[mi] = -1e30f;
      lrowL[mi] = 0.f;
    }

    for (int kt = 0; kt <= qt; kt++) {
      const int k0 = kt * 128;
      const bool diag = (kt == qt);
      __syncthreads();
#pragma unroll
      for (int i = 0; i < 4; i++) {
        int idx = tid + i * 256;
        int row = idx >> 3, c8 = (idx & 7) << 3;
        *(us8*)(sK + row * 72 + c8) = *(const us8*)(Kp + (size_t)(k0 + row) * DK + c8);
      }
#pragma unroll
      for (int i = 0; i < 4; i++) {
        int idx = tid + i * 256;
        int row = idx >> 4, cc = (idx & 15) << 3;
        *(us8*)(sV + row * 136 + cc) = *(const us8*)(Vp + (size_t)row * SS + k0 + cc);
      }
      __syncthreads();

      // S^T: sc[mi][kti] has col=l16=q, row k = kti*16 + quad*4 + r
      f32x4 sc[2][8];
#pragma unroll
      for (int mi = 0; mi < 2; mi++)
#pragma unroll
        for (int kti = 0; kti < 8; kti++) sc[mi][kti] = f32x4{0.f, 0.f, 0.f, 0.f};
#pragma unroll
      for (int kti = 0; kti < 8; kti++) {
#pragma unroll
        for (int kk = 0; kk < 2; kk++) {
          bf16x8 ak = ld_frag(sK + (kti * 16 + l16) * 72 + kk * 32 + quad * 8);
#pragma unroll
          for (int mi = 0; mi < 2; mi++) sc[mi][kti] = MFMA_BF16(ak, aq[mi][kk], sc[mi][kti]);
        }
      }

      // scale (exp2 domain); causal mask only on diagonal tile
      if (diag) {
#pragma unroll
        for (int mi = 0; mi < 2; mi++) {
          int ql = wq0 + mi * 16 + l16;  // local q
#pragma unroll
          for (int kti = 0; kti < 8; kti++)
#pragma unroll
            for (int r = 0; r < 4; r++) {
              int kl = kti * 16 + quad * 4 + r;
              float v = sc[mi][kti][r] * sl;
              sc[mi][kti][r] = (kl > ql) ? -1e30f : v;
            }
        }
      } else {
#pragma unroll
        for (int mi = 0; mi < 2; mi++)
#pragma unroll
          for (int kti = 0; kti < 8; kti++)
#pragma unroll
            for (int r = 0; r < 4; r++) sc[mi][kti][r] *= sl;
      }

      // online softmax: in-lane max over 32 k, reduce across the 4 quads
      float alphaL[2];
#pragma unroll
      for (int mi = 0; mi < 2; mi++) {
        f32x4 vm = sc[mi][0];
#pragma unroll
        for (int kti = 1; kti < 8; kti++)
#pragma unroll
          for (int r = 0; r < 4; r++) vm[r] = fmaxf(vm[r], sc[mi][kti][r]);
        float mx = fmaxf(fmaxf(vm[0], vm[1]), fmaxf(vm[2], vm[3]));
        mx = fmaxf(mx, __shfl_xor(mx, 16, 64));
        mx = fmaxf(mx, __shfl_xor(mx, 32, 64));
        float mnew = fmaxf(mrowL[mi], mx);
        alphaL[mi] = exp2f(mrowL[mi] - mnew);
        mrowL[mi] = mnew;
      }

      // per mi: rescale O, build packed P in regs, PV with permuted k-order:
      // chunk c: k_mfma(quad,j) = 32c + 16*(j>=4) + quad*4 + (j&3), same for A,B.
#pragma unroll
      for (int mi = 0; mi < 2; mi++) {
#pragma unroll
        for (int r = 0; r < 4; r++) {
          float a = __shfl(alphaL[mi], quad * 4 + r, 64);
#pragma unroll
          for (int ni = 0; ni < 4; ni++) o_acc[mi][ni][r] *= a;
        }
        us4 pk[8];
        f32x4 vs = f32x4{0.f, 0.f, 0.f, 0.f};
#pragma unroll
        for (int kti = 0; kti < 8; kti++) {
#pragma unroll
          for (int r = 0; r < 4; r++) {
            float p = exp2f(sc[mi][kti][r] - mrowL[mi]);
            vs[r] += p;
            pk[kti][r] = f2bf(p);
          }
        }
        float ls = (vs[0] + vs[1]) + (vs[2] + vs[3]);
        ls += __shfl_xor(ls, 16, 64);
        ls += __shfl_xor(ls, 32, 64);
        lrowL[mi] = lrowL[mi] * alphaL[mi] + ls;

#pragma unroll
        for (int c = 0; c < 4; c++) {
          bf16x8 ap = __builtin_bit_cast(
              bf16x8, __builtin_shufflevector(pk[2 * c], pk[2 * c + 1], 0, 1, 2, 3, 4, 5, 6, 7));
#pragma unroll
          for (int ni = 0; ni < 4; ni++) {
            const unsigned short* vb = sV + (ni * 16 + l16) * 136 + c * 32 + quad * 4;
            us4 lo = *(const us4*)vb;
            us4 hi = *(const us4*)(vb + 16);
            bf16x8 bfr = __builtin_bit_cast(
                bf16x8, __builtin_shufflevector(lo, hi, 0, 1, 2, 3, 4, 5, 6, 7));
            o_acc[mi][ni] = MFMA_BF16(ap, bfr, o_acc[mi][ni]);
          }
        }
      }
    }

    // epilogue: O/l -> concat layout channel h*64 + dk
#pragma unroll
    for (int mi = 0; mi < 2; mi++) {
#pragma unroll
      for (int r = 0; r < 4; r++) {
        float lr = __shfl(lrowL[mi], quad * 4 + r, 64);
        float inv = 1.0f / lr;
        int qg = q0 + wq0 + mi * 16 + quad * 4 + r;
        size_t rowbase = ((size_t)(b * SS + qg)) * DD + h * DK;
#pragma unroll
        for (int ni = 0; ni < 4; ni++) {
          int dk = ni * 16 + l16;
          outc[rowbase + dk] = f2bf(o_acc[mi][ni][r] * inv);
        }
      }
    }
    __syncthreads();  // protect sK/sV before second pass restages
  }
}

// ---------------------------------------------------------------------------
// K3: output projection. 128x128 tile, BK=64 two-half, both operands gl_lds.
// out[m,n] = sum_k AC[m,k] * Wo[n,k] + bo[n]  (fp32 out)
// ---------------------------------------------------------------------------
__global__ __launch_bounds__(256, 4) void out_proj(
    const unsigned short* __restrict__ ac, const unsigned short* __restrict__ wo,
    const float* __restrict__ bias, float* __restrict__ out) {
  const int m0 = blockIdx.x * 128;
  const int n0 = blockIdx.y * 128;
  __shared__ unsigned short sA[8192];  // [2][128*32]
  __shared__ unsigned short sB[8192];

  const int tid = threadIdx.x;
  const int lane = tid & 63;
  const int wave = tid >> 6;
  const int wm = wave & 1, wn = wave >> 1;
  const int quad = lane >> 4, l16 = lane & 15;

  f32x4 acc[4][4];
#pragma unroll
  for (int i = 0; i < 4; i++)
#pragma unroll
    for (int j = 0; j < 4; j++) acc[i][j] = f32x4{0.f, 0.f, 0.f, 0.f};

  for (int k0 = 0; k0 < DD; k0 += 64) {
    __syncthreads();
#pragma unroll
    for (int j = 0; j < 4; j++) {
      int cid = tid + j * 256;
      int half = cid >> 9;
      int rr = (cid & 511) >> 2;
      int c8 = (cid & 3) << 3;
      gl_lds16(ac + (size_t)(m0 + rr) * DD + k0 + half * 32 + c8,
               sA + half * 4096 + rr * 32 + c8);
    }
#pragma unroll
    for (int j = 0; j < 4; j++) {
      int cid = tid + j * 256;
      int half = cid >> 9;
      int rr = (cid & 511) >> 2;
      int c8 = (cid & 3) << 3;
      gl_lds16(wo + (size_t)(n0 + rr) * DD + k0 + half * 32 + c8,
               sB + half * 4096 + rr * 32 + c8);
    }
    __syncthreads();
#pragma unroll
    for (int kk = 0; kk < 2; kk++) {
      bf16x8 af[4];
#pragma unroll
      for (int mi = 0; mi < 4; mi++)
        af[mi] = ld_frag(sA + kk * 4096 + (wm * 64 + mi * 16 + l16) * 32 + quad * 8);
#pragma unroll
      for (int ni = 0; ni < 4; ni++) {
        bf16x8 bfr = ld_frag(sB + kk * 4096 + (wn * 64 + ni * 16 + l16) * 32 + quad * 8);
#pragma unroll
        for (int mi = 0; mi < 4; mi++) acc[mi][ni] = MFMA_BF16(af[mi], bfr, acc[mi][ni]);
      }
    }
  }

#pragma unroll
  for (int mi = 0; mi < 4; mi++) {
#pragma unroll
    for (int ni = 0; ni < 4; ni++) {
      int n = n0 + wn * 64 + ni * 16 + l16;
      float bvv = bias[n];
      int mg0 = m0 + wm * 64 + mi * 16 + quad * 4;
#pragma unroll
      for (int r = 0; r < 4; r++) out[(size_t)(mg0 + r) * DD + n] = acc[mi][ni][r] + bvv;
    }
  }
}

// ---------------------------------------------------------------------------
extern "C" void kernel_launch(void* const* d_in, const int* in_sizes, int n_in,
                              void* d_out, int out_size, void* d_ws, size_t ws_size,
                              hipStream_t stream) {
  const float* q_in = (const float*)d_in[0];
  const float* k_in = (const float*)d_in[1];
  const float* v_in = (const float*)d_in[2];
  // d_in[3] = mask: deterministic causal tril, handled analytically in attn()
  const float* w_q = (const float*)d_in[4];
  const float* b_q = (const float*)d_in[5];
  const float* w_k = (const float*)d_in[6];
  const float* b_k = (const float*)d_in[7];
  const float* w_v = (const float*)d_in[8];
  const float* b_v = (const float*)d_in[9];
  const float* w_o = (const float*)d_in[10];
  const float* b_o = (const float*)d_in[11];
  float* out = (float*)d_out;

  // ws layout (ushort elems), 36M = 72 MB:
  // wb[0,4M) | qh[4M,12M) | kh[12M,20M) | vt[20M,28M) | outc[28M,36M)
  unsigned short* ws = (unsigned short*)d_ws;
  unsigned short* wb = ws;
  unsigned short* qh = ws + (size_t)4 * 1024 * 1024;
  unsigned short* kh = ws + (size_t)12 * 1024 * 1024;
  unsigned short* vt = ws + (size_t)20 * 1024 * 1024;
  unsigned short* outc = ws + (size_t)28 * 1024 * 1024;

  const size_t WSZ = (size_t)DD * DD;

  cvt_weights<<<dim3(1024, 4), 256, 0, stream>>>(w_q, w_k, w_v, w_o, wb);
  qkv_gemm<<<dim3(64, 8, 3), 256, 0, stream>>>(q_in, k_in, v_in, wb, b_q, b_k, b_v, qh, kh, vt);
  attn<<<dim3(64, 8), 256, 0, stream>>>(qh, kh, vt, outc);
  out_proj<<<dim3(64, 8), 256, 0, stream>>>(outc, wb + 3 * WSZ, b_o, out);
}